// Round 3
// baseline (587.632 us; speedup 1.0000x reference)
//
#include <hip/hip_runtime.h>
#include <hip/hip_bf16.h>

// Problem constants (B=4096, D=1024 per reference setup_inputs)
#define B_ROWS 4096
#define D_DIM  1024
#define N_ROWS 8192          // 2B
#define TEMP_INV 2.0f        // 1 / 0.5

typedef __attribute__((ext_vector_type(8)))  short bf16x8;  // 8 bf16 = 4 VGPRs
typedef __attribute__((ext_vector_type(16))) float f32x16;  // 32x32 MFMA C/D frag

__device__ inline ushort f2bf(float f) {
    union { float f; unsigned u; } v; v.f = f;
    unsigned r = v.u + 0x7fff + ((v.u >> 16) & 1);   // RNE
    return (ushort)(r >> 16);
}

// Async global->LDS DMA, 16 B per lane. LDS dest is WAVE-UNIFORM base;
// lane i's 16 B land at base + i*16 (per-lane global addr is free-form).
__device__ inline void load_lds16(const ushort* g, ushort* l) {
    __builtin_amdgcn_global_load_lds(
        (const __attribute__((address_space(1))) unsigned int*)g,
        (__attribute__((address_space(3))) unsigned int*)l,
        16, 0, 0);
}

// ---------------------------------------------------------------------------
// Kernel 1: wave-per-row L2 normalize. Block = 4 waves = 4 row pairs.
// Writes normalized bf16 reps [8192][1024], pos[b] = z_i(b).z_j(b),
// zeroes denom[8192] and the completion counter.
// ---------------------------------------------------------------------------
__global__ __launch_bounds__(256)
void normalize_kernel(const float* __restrict__ emb_i,
                      const float* __restrict__ emb_j,
                      ushort* __restrict__ reps,
                      float* __restrict__ pos,
                      float* __restrict__ denom,
                      unsigned int* __restrict__ counter) {
    const int t    = threadIdx.x;
    const int lane = t & 63;
    const int wave = t >> 6;
    const int b    = blockIdx.x * 4 + wave;          // 0..4095

    if (blockIdx.x < N_ROWS / 256) denom[blockIdx.x * 256 + t] = 0.0f;
    if (blockIdx.x == 0 && t == 0) counter[0] = 0u;

    const float4* pi = (const float4*)(emb_i + (size_t)b * D_DIM) + lane * 4;
    const float4* pj = (const float4*)(emb_j + (size_t)b * D_DIM) + lane * 4;

    float4 vi[4], vj[4];
    float si = 0.f, sj = 0.f, sd = 0.f;
    #pragma unroll
    for (int k = 0; k < 4; k++) {
        vi[k] = pi[k]; vj[k] = pj[k];
        si += vi[k].x*vi[k].x + vi[k].y*vi[k].y + vi[k].z*vi[k].z + vi[k].w*vi[k].w;
        sj += vj[k].x*vj[k].x + vj[k].y*vj[k].y + vj[k].z*vj[k].z + vj[k].w*vj[k].w;
        sd += vi[k].x*vj[k].x + vi[k].y*vj[k].y + vi[k].z*vj[k].z + vi[k].w*vj[k].w;
    }
    #pragma unroll
    for (int off = 32; off >= 1; off >>= 1) {   // butterfly: all lanes get sums
        si += __shfl_xor(si, off);
        sj += __shfl_xor(sj, off);
        sd += __shfl_xor(sd, off);
    }
    const float inv_i = 1.0f / fmaxf(sqrtf(si), 1e-12f);
    const float inv_j = 1.0f / fmaxf(sqrtf(sj), 1e-12f);
    if (lane == 0) pos[b] = sd * inv_i * inv_j;

    ushort oi[16], oj[16];
    #pragma unroll
    for (int k = 0; k < 4; k++) {
        oi[4*k+0] = f2bf(vi[k].x * inv_i); oi[4*k+1] = f2bf(vi[k].y * inv_i);
        oi[4*k+2] = f2bf(vi[k].z * inv_i); oi[4*k+3] = f2bf(vi[k].w * inv_i);
        oj[4*k+0] = f2bf(vj[k].x * inv_j); oj[4*k+1] = f2bf(vj[k].y * inv_j);
        oj[4*k+2] = f2bf(vj[k].z * inv_j); oj[4*k+3] = f2bf(vj[k].w * inv_j);
    }
    ushort* ri = reps + (size_t)b * D_DIM + lane * 16;
    ushort* rj = reps + (size_t)(b + B_ROWS) * D_DIM + lane * 16;
    *(bf16x8*)(ri)     = *(bf16x8*)(oi);
    *(bf16x8*)(ri + 8) = *(bf16x8*)(oi + 8);
    *(bf16x8*)(rj)     = *(bf16x8*)(oj);
    *(bf16x8*)(rj + 8) = *(bf16x8*)(oj + 8);
}

// ---------------------------------------------------------------------------
// Kernel 2: fused sim = Z.Z^T -> exp(s/T) -> diag-mask -> column-sum into
// denom[] (sim symmetric: col sums == row sums), then last-to-finish block
// computes the scalar loss (saves a launch).
// 128x128 tile/block, grid 64x64 tiles. BK=32, 32x32x16 bf16 MFMA (2x2/wave,
// 20% better FLOP/cyc than 16x16x32, half the input regs).
// LDS: row stride 32 bf16 (64 B, no pad — global_load_lds requirement);
// chunk c (16 B) of row r stored at slot c ^ ((r>>1)&3) (swizzle applied on
// the GLOBAL source address; proven conflict-free in R2).
// rt = blockIdx>>6: 64 consecutive blocks share a row-panel -> same-XCD L2 reuse.
// ---------------------------------------------------------------------------
#define BM 128
#define BN 128
#define BK 32

__global__ __launch_bounds__(256, 3)
void sim_denom_kernel(const ushort* __restrict__ reps,
                      float* __restrict__ denom,
                      const float* __restrict__ pos,
                      unsigned int* __restrict__ counter,
                      float* __restrict__ out) {
    const int rt = blockIdx.x >> 6;       // row tile
    const int ct = blockIdx.x & 63;       // col tile
    const int rowBase = rt * BM;
    const int colBase = ct * BN;

    const int t    = threadIdx.x;
    const int lane = t & 63;
    const int wave = t >> 6;
    const int wr   = wave >> 1;           // wave row quadrant (0/1)
    const int wc   = wave & 1;            // wave col quadrant (0/1)
    const int half = lane >> 5;           // k-half selector (0/1)
    const int l31  = lane & 31;

    __shared__ ushort Asmem[BM * BK];     // 8 KB, row stride 32 bf16
    __shared__ ushort Bsmem[BN * BK];     // 8 KB

    // staging lane map: lane i loads row seg*16+(i>>2), global chunk
    // (i&3)^((i>>3)&3), landing at LDS slot (i&3) of that row.
    const int rl = lane >> 2;
    const int cg = (lane & 3) ^ ((lane >> 3) & 3);
    const int seg0 = wave * 2, seg1 = wave * 2 + 1;
    const ushort* gA0 = reps + (size_t)(rowBase + seg0 * 16 + rl) * D_DIM + cg * 8;
    const ushort* gA1 = reps + (size_t)(rowBase + seg1 * 16 + rl) * D_DIM + cg * 8;
    const ushort* gB0 = reps + (size_t)(colBase + seg0 * 16 + rl) * D_DIM + cg * 8;
    const ushort* gB1 = reps + (size_t)(colBase + seg1 * 16 + rl) * D_DIM + cg * 8;

    // LDS read offsets (ushort units) for 32x32x16 fragments:
    // A[m][k]: m = l31 (row of tile), k = half*8 + j  -> chunk c = ks*2 + half
    // stored slot = c ^ ((r>>1)&3); offset = r*32 + slot*8
    int aoff[2][2], boff[2][2];           // [ks][mi/ni]
    #pragma unroll
    for (int ks = 0; ks < 2; ks++)
        #pragma unroll
        for (int i = 0; i < 2; i++) {
            const int ra = wr * 64 + i * 32 + l31;
            const int rb = wc * 64 + i * 32 + l31;
            const int c  = ks * 2 + half;
            aoff[ks][i] = ra * 32 + (c ^ ((ra >> 1) & 3)) * 8;
            boff[ks][i] = rb * 32 + (c ^ ((rb >> 1) & 3)) * 8;
        }

    f32x16 acc[2][2];
    #pragma unroll
    for (int mi = 0; mi < 2; mi++)
        #pragma unroll
        for (int ni = 0; ni < 2; ni++)
            #pragma unroll
            for (int r = 0; r < 16; r++) acc[mi][ni][r] = 0.f;

    for (int kb = 0; kb < D_DIM; kb += BK) {
        __syncthreads();   // prev iter's ds_reads done before overwrite
        load_lds16(gA0 + kb, Asmem + seg0 * 512);
        load_lds16(gA1 + kb, Asmem + seg1 * 512);
        load_lds16(gB0 + kb, Bsmem + seg0 * 512);
        load_lds16(gB1 + kb, Bsmem + seg1 * 512);
        __syncthreads();   // drains vmcnt (compiler-inserted waitcnt)

        bf16x8 af[2][2], bfr[2][2];
        #pragma unroll
        for (int ks = 0; ks < 2; ks++)
            #pragma unroll
            for (int i = 0; i < 2; i++) {
                af[ks][i]  = *(const bf16x8*)(Asmem + aoff[ks][i]);
                bfr[ks][i] = *(const bf16x8*)(Bsmem + boff[ks][i]);
            }
        #pragma unroll
        for (int ks = 0; ks < 2; ks++)
            #pragma unroll
            for (int mi = 0; mi < 2; mi++)
                #pragma unroll
                for (int ni = 0; ni < 2; ni++)
                    acc[mi][ni] = __builtin_amdgcn_mfma_f32_32x32x16_bf16(
                        af[ks][mi], bfr[ks][ni], acc[mi][ni], 0, 0, 0);
    }

    // Epilogue: e = exp(s/T), mask diagonal, per-lane partial column sums.
    // C/D layout (32x32): col = l31, row = (reg&3) + 8*(reg>>2) + 4*half.
    float csum[2] = {0.f, 0.f};
    #pragma unroll
    for (int mi = 0; mi < 2; mi++) {
        const int rbase = rowBase + wr * 64 + mi * 32 + half * 4;
        #pragma unroll
        for (int ni = 0; ni < 2; ni++) {
            const int col = colBase + wc * 64 + ni * 32 + l31;
            const f32x16 a = acc[mi][ni];
            #pragma unroll
            for (int reg = 0; reg < 16; reg++) {
                const int row = rbase + (reg & 3) + 8 * (reg >> 2);
                float e = __expf(a[reg] * TEMP_INV);
                if (row == col) e = 0.0f;   // neg_mask diagonal
                csum[ni] += e;
            }
        }
    }
    #pragma unroll
    for (int ni = 0; ni < 2; ni++) {
        const float v = csum[ni] + __shfl_xor(csum[ni], 32);
        if (half == 0)
            atomicAdd(denom + colBase + wc * 64 + ni * 32 + l31, v);
    }

    // Completion: last block to finish computes the loss.
    __threadfence();
    __syncthreads();
    __shared__ unsigned int done;
    if (t == 0) done = atomicAdd(counter, 1u);
    __syncthreads();
    if (done == (unsigned)(64 * 64 - 1)) {
        __threadfence();
        float s = 0.f;
        for (int i = t; i < N_ROWS; i += 256) {
            const float d = __hip_atomic_load(denom + i, __ATOMIC_RELAXED,
                                              __HIP_MEMORY_SCOPE_AGENT);
            s += logf(d) - pos[i & (B_ROWS - 1)] * TEMP_INV;
        }
        #pragma unroll
        for (int off = 32; off >= 1; off >>= 1) s += __shfl_xor(s, off);
        __shared__ float red[4];
        if ((t & 63) == 0) red[t >> 6] = s;
        __syncthreads();
        if (t == 0) out[0] = (red[0] + red[1] + red[2] + red[3]) / (float)N_ROWS;
    }
}

// ---------------------------------------------------------------------------
extern "C" void kernel_launch(void* const* d_in, const int* in_sizes, int n_in,
                              void* d_out, int out_size, void* d_ws, size_t ws_size,
                              hipStream_t stream) {
    const float* emb_i = (const float*)d_in[0];
    const float* emb_j = (const float*)d_in[1];

    ushort* reps  = (ushort*)d_ws;                                    // 16 MB bf16 [8192][1024]
    float*  pos   = (float*)((char*)d_ws + (size_t)N_ROWS * D_DIM * sizeof(ushort)); // 16 KB
    float*  denom = pos + B_ROWS;                                     // 32 KB
    unsigned int* counter = (unsigned int*)(denom + N_ROWS);          // 4 B
    float*  out   = (float*)d_out;

    normalize_kernel<<<B_ROWS / 4, 256, 0, stream>>>(emb_i, emb_j, reps, pos, denom, counter);
    sim_denom_kernel<<<64 * 64, 256, 0, stream>>>(reps, denom, pos, counter, out);
}

// Round 4
// 339.375 us; speedup vs baseline: 1.7315x; 1.7315x over previous
//
#include <hip/hip_runtime.h>
#include <hip/hip_bf16.h>

// Problem constants (B=4096, D=1024 per reference setup_inputs)
#define B_ROWS 4096
#define D_DIM  1024
#define N_ROWS 8192          // 2B
#define TEMP_INV 2.0f        // 1 / 0.5

#define NTILE 64             // 8192 / 128 row/col tiles
#define KOFF  33             // offsets 0..32 (wrap pairing)
#define GRID_SIM (NTILE * KOFF)   // 2112 blocks

typedef __attribute__((ext_vector_type(8))) short  bf16x8;  // 8 bf16 = 4 VGPRs
typedef __attribute__((ext_vector_type(4))) float  f32x4;   // MFMA C/D frag

__device__ inline ushort f2bf(float f) {
    union { float f; unsigned u; } v; v.f = f;
    unsigned r = v.u + 0x7fff + ((v.u >> 16) & 1);   // RNE
    return (ushort)(r >> 16);
}

// Async global->LDS DMA, 16 B per lane. LDS dest is WAVE-UNIFORM base;
// lane i's 16 B land at base + i*16 (per-lane global addr is free-form).
__device__ inline void load_lds16(const ushort* g, ushort* l) {
    __builtin_amdgcn_global_load_lds(
        (const __attribute__((address_space(1))) unsigned int*)g,
        (__attribute__((address_space(3))) unsigned int*)l,
        16, 0, 0);
}

// ---------------------------------------------------------------------------
// Kernel 1: wave-per-row L2 normalize. Block = 4 waves = 4 row pairs.
// Writes normalized bf16 reps [8192][1024], pos[b] = z_i(b).z_j(b),
// zeroes denom[8192] and the completion counter.
// ---------------------------------------------------------------------------
__global__ __launch_bounds__(256)
void normalize_kernel(const float* __restrict__ emb_i,
                      const float* __restrict__ emb_j,
                      ushort* __restrict__ reps,
                      float* __restrict__ pos,
                      float* __restrict__ denom,
                      unsigned int* __restrict__ counter) {
    const int t    = threadIdx.x;
    const int lane = t & 63;
    const int wave = t >> 6;
    const int b    = blockIdx.x * 4 + wave;          // 0..4095

    if (blockIdx.x < N_ROWS / 256) denom[blockIdx.x * 256 + t] = 0.0f;
    if (blockIdx.x == 0 && t == 0) counter[0] = 0u;

    const float4* pi = (const float4*)(emb_i + (size_t)b * D_DIM) + lane * 4;
    const float4* pj = (const float4*)(emb_j + (size_t)b * D_DIM) + lane * 4;

    float4 vi[4], vj[4];
    float si = 0.f, sj = 0.f, sd = 0.f;
    #pragma unroll
    for (int k = 0; k < 4; k++) {
        vi[k] = pi[k]; vj[k] = pj[k];
        si += vi[k].x*vi[k].x + vi[k].y*vi[k].y + vi[k].z*vi[k].z + vi[k].w*vi[k].w;
        sj += vj[k].x*vj[k].x + vj[k].y*vj[k].y + vj[k].z*vj[k].z + vj[k].w*vj[k].w;
        sd += vi[k].x*vj[k].x + vi[k].y*vj[k].y + vi[k].z*vj[k].z + vi[k].w*vj[k].w;
    }
    #pragma unroll
    for (int off = 32; off >= 1; off >>= 1) {   // butterfly: all lanes get sums
        si += __shfl_xor(si, off);
        sj += __shfl_xor(sj, off);
        sd += __shfl_xor(sd, off);
    }
    const float inv_i = 1.0f / fmaxf(sqrtf(si), 1e-12f);
    const float inv_j = 1.0f / fmaxf(sqrtf(sj), 1e-12f);
    if (lane == 0) pos[b] = sd * inv_i * inv_j;

    ushort oi[16], oj[16];
    #pragma unroll
    for (int k = 0; k < 4; k++) {
        oi[4*k+0] = f2bf(vi[k].x * inv_i); oi[4*k+1] = f2bf(vi[k].y * inv_i);
        oi[4*k+2] = f2bf(vi[k].z * inv_i); oi[4*k+3] = f2bf(vi[k].w * inv_i);
        oj[4*k+0] = f2bf(vj[k].x * inv_j); oj[4*k+1] = f2bf(vj[k].y * inv_j);
        oj[4*k+2] = f2bf(vj[k].z * inv_j); oj[4*k+3] = f2bf(vj[k].w * inv_j);
    }
    ushort* ri = reps + (size_t)b * D_DIM + lane * 16;
    ushort* rj = reps + (size_t)(b + B_ROWS) * D_DIM + lane * 16;
    *(bf16x8*)(ri)     = *(bf16x8*)(oi);
    *(bf16x8*)(ri + 8) = *(bf16x8*)(oi + 8);
    *(bf16x8*)(rj)     = *(bf16x8*)(oj);
    *(bf16x8*)(rj + 8) = *(bf16x8*)(oj + 8);
}

// ---------------------------------------------------------------------------
// Kernel 2: SYMMETRY-HALVED fused sim -> exp(s/T) -> denom accumulation.
// sim = Z.Z^T is symmetric: compute only upper-triangle 128x128 tiles.
// Off-diagonal tile (rt<ct): add its column sums to denom[cols] AND its row
// sums to denom[rows] (covers the mirror tile (ct,rt)). Diagonal tile: column
// sums only (tile itself symmetric), self-mask, B-stage skipped (B==A).
// Pair mapping: block b -> (rt0 = b/33, k = b%33), tile {rt0, (rt0+k)&63};
// k=32 pairs are generated twice -> blocks with k==32 && rt0>=32 skip.
// Structure = R2's proven kernel: 16x16x32 MFMA, BK=32, global_load_lds w16,
// XOR chunk swizzle (measured 0 bank conflicts). No launch_bounds pressure
// (R3 lesson: forcing 3 waves/EU spilled fragments to scratch, 2.5x slower).
// Last block to finish computes the scalar loss.
// ---------------------------------------------------------------------------
#define BM 128
#define BK 32

__global__ __launch_bounds__(256)
void sim_denom_kernel(const ushort* __restrict__ reps,
                      float* __restrict__ denom,
                      const float* __restrict__ pos,
                      unsigned int* __restrict__ counter,
                      float* __restrict__ out) {
    const int bid = blockIdx.x;
    const int rt0 = bid / KOFF;
    const int k   = bid - rt0 * KOFF;
    const int o2  = (rt0 + k) & (NTILE - 1);
    const int rt  = min(rt0, o2);
    const int ct  = max(rt0, o2);
    const bool skip   = (k == 32 && rt0 >= 32);   // duplicate of (rt0-32)'s pair
    const bool isDiag = (k == 0);

    const int t    = threadIdx.x;
    const int lane = t & 63;
    const int wave = t >> 6;

    __shared__ ushort Asmem[BM * BK];     // 8 KB, row stride 32 bf16
    __shared__ ushort Bsmem[BM * BK];     // 8 KB
    __shared__ unsigned int done;
    __shared__ float red[4];

    if (!skip) {
        const int rowBase = rt * BM;
        const int colBase = ct * BM;
        const int wr   = wave >> 1;           // wave row quadrant (0/1)
        const int wc   = wave & 1;            // wave col quadrant (0/1)
        const int quad = lane >> 4;           // 0..3
        const int l15  = lane & 15;

        // staging lane map (R2-proven): lane i loads row seg*16+(i>>2), global
        // chunk (i&3)^((i>>3)&3), landing at LDS slot (i&3) of that row.
        const int rl = lane >> 2;
        const int cg = (lane & 3) ^ ((lane >> 3) & 3);
        const int seg0 = wave * 2, seg1 = wave * 2 + 1;
        const ushort* gA0 = reps + (size_t)(rowBase + seg0 * 16 + rl) * D_DIM + cg * 8;
        const ushort* gA1 = reps + (size_t)(rowBase + seg1 * 16 + rl) * D_DIM + cg * 8;
        const ushort* gB0 = reps + (size_t)(colBase + seg0 * 16 + rl) * D_DIM + cg * 8;
        const ushort* gB1 = reps + (size_t)(colBase + seg1 * 16 + rl) * D_DIM + cg * 8;
        const ushort* Bbase = isDiag ? Asmem : Bsmem;   // diag: B tile == A tile

        f32x4 acc[4][4];
        #pragma unroll
        for (int mi = 0; mi < 4; mi++)
            #pragma unroll
            for (int ni = 0; ni < 4; ni++)
                acc[mi][ni] = (f32x4){0.f, 0.f, 0.f, 0.f};

        for (int kb = 0; kb < D_DIM; kb += BK) {
            __syncthreads();   // prev iter's ds_reads done before overwrite
            load_lds16(gA0 + kb, Asmem + seg0 * 512);
            load_lds16(gA1 + kb, Asmem + seg1 * 512);
            if (!isDiag) {
                load_lds16(gB0 + kb, Bsmem + seg0 * 512);
                load_lds16(gB1 + kb, Bsmem + seg1 * 512);
            }
            __syncthreads();   // drains vmcnt (compiler-inserted waitcnt)

            bf16x8 af[4], bfr[4];
            #pragma unroll
            for (int mi = 0; mi < 4; mi++) {
                const int r = wr * 64 + mi * 16 + l15;
                af[mi] = *(const bf16x8*)(Asmem + r * 32 + (quad ^ ((r >> 1) & 3)) * 8);
            }
            #pragma unroll
            for (int ni = 0; ni < 4; ni++) {
                const int r = wc * 64 + ni * 16 + l15;
                bfr[ni] = *(const bf16x8*)(Bbase + r * 32 + (quad ^ ((r >> 1) & 3)) * 8);
            }

            #pragma unroll
            for (int mi = 0; mi < 4; mi++)
                #pragma unroll
                for (int ni = 0; ni < 4; ni++)
                    acc[mi][ni] = __builtin_amdgcn_mfma_f32_16x16x32_bf16(
                        af[mi], bfr[ni], acc[mi][ni], 0, 0, 0);
        }

        // Epilogue. C layout: col = lane&15, row = quad*4 + reg.
        // csum[ni]: per-lane partial column sums; prs[mi][r]: partial row sums.
        float csum[4] = {0.f, 0.f, 0.f, 0.f};
        float prs[4][4];
        #pragma unroll
        for (int mi = 0; mi < 4; mi++)
            #pragma unroll
            for (int r = 0; r < 4; r++) prs[mi][r] = 0.f;

        #pragma unroll
        for (int mi = 0; mi < 4; mi++) {
            const int rowA = rowBase + wr * 64 + mi * 16 + quad * 4;
            #pragma unroll
            for (int ni = 0; ni < 4; ni++) {
                const int col = colBase + wc * 64 + ni * 16 + l15;
                const f32x4 a = acc[mi][ni];
                #pragma unroll
                for (int r = 0; r < 4; r++) {
                    float e = __expf(a[r] * TEMP_INV);
                    if (isDiag && rowA + r == col) e = 0.0f;   // self-sim mask
                    csum[ni] += e;
                    prs[mi][r] += e;
                }
            }
        }
        // column sums -> denom[col] (reduce across the 4 quads)
        #pragma unroll
        for (int ni = 0; ni < 4; ni++) {
            float v = csum[ni];
            v += __shfl_xor(v, 16);
            v += __shfl_xor(v, 32);
            if (quad == 0)
                atomicAdd(denom + colBase + wc * 64 + ni * 16 + l15, v);
        }
        // row sums -> denom[row] (mirror-tile contribution; off-diag only)
        if (!isDiag) {
            #pragma unroll
            for (int mi = 0; mi < 4; mi++)
                #pragma unroll
                for (int r = 0; r < 4; r++) {
                    float v = prs[mi][r];
                    v += __shfl_xor(v, 1);
                    v += __shfl_xor(v, 2);
                    v += __shfl_xor(v, 4);
                    v += __shfl_xor(v, 8);
                    if (l15 == 0)
                        atomicAdd(denom + rowBase + wr * 64 + mi * 16 + quad * 4 + r, v);
                }
        }
    }

    // Completion: last block to finish computes the loss.
    __threadfence();
    __syncthreads();
    if (t == 0) done = atomicAdd(counter, 1u);
    __syncthreads();
    if (done == (unsigned)(GRID_SIM - 1)) {
        __threadfence();
        float s = 0.f;
        for (int i = t; i < N_ROWS; i += 256) {
            const float d = __hip_atomic_load(denom + i, __ATOMIC_RELAXED,
                                              __HIP_MEMORY_SCOPE_AGENT);
            s += logf(d) - pos[i & (B_ROWS - 1)] * TEMP_INV;
        }
        #pragma unroll
        for (int off = 32; off >= 1; off >>= 1) s += __shfl_xor(s, off);
        if ((t & 63) == 0) red[t >> 6] = s;
        __syncthreads();
        if (t == 0) out[0] = (red[0] + red[1] + red[2] + red[3]) / (float)N_ROWS;
    }
}

// ---------------------------------------------------------------------------
extern "C" void kernel_launch(void* const* d_in, const int* in_sizes, int n_in,
                              void* d_out, int out_size, void* d_ws, size_t ws_size,
                              hipStream_t stream) {
    const float* emb_i = (const float*)d_in[0];
    const float* emb_j = (const float*)d_in[1];

    ushort* reps  = (ushort*)d_ws;                                    // 16 MB bf16 [8192][1024]
    float*  pos   = (float*)((char*)d_ws + (size_t)N_ROWS * D_DIM * sizeof(ushort)); // 16 KB
    float*  denom = pos + B_ROWS;                                     // 32 KB
    unsigned int* counter = (unsigned int*)(denom + N_ROWS);          // 4 B
    float*  out   = (float*)d_out;

    normalize_kernel<<<B_ROWS / 4, 256, 0, stream>>>(emb_i, emb_j, reps, pos, denom, counter);
    sim_denom_kernel<<<GRID_SIM, 256, 0, stream>>>(reps, denom, pos, counter, out);
}